// Round 1
// baseline (560.981 us; speedup 1.0000x reference)
//
#include <hip/hip_runtime.h>
#include <stdint.h>

// GNN: 2-layer GCN + skip + classifier head. All fp32 in/out; edge_index int32.
// N=100000, E=1600000, F=H=128, OUT=40.
//
// Round-11: panel-partitioned aggregation. h' stored PANEL-MAJOR [8][N][16] bf16
// (32 B per row per panel, 3.2 MB slab). Aggregate blocks pin panel p to XCD p via
// blockIdx&7 so each XCD's gather working set is L2-resident (4 MB/XCD), attacking
// the ~3 TB/s L2-miss-fill wall the round-9 kernel sits on (fetch 203 MB == the
// unique-lines-per-XCD combinatorial floor for whole-row gathers).

#define HID 128
#define OUTD 40
#define BSH 8                 // 256 nodes per bucket
#define BCAP 6144             // LDS colbuf entries per bucket (mean ~4350)
#define EPB 8192              // edges per scatter block
#define NBMAX 512

typedef __attribute__((ext_vector_type(8))) short short8;
typedef __attribute__((ext_vector_type(4))) float f32x4;
typedef __attribute__((ext_vector_type(2))) float f32x2;
typedef __attribute__((ext_vector_type(4))) unsigned int u32x4;

__device__ inline uint16_t f32_to_bf16(float f) {
    uint32_t u = __float_as_uint(f);
    uint32_t r = u + 0x7FFFu + ((u >> 16) & 1u);
    return (uint16_t)(r >> 16);
}
__device__ inline uint32_t pack_bf16x2(float lo, float hi) {
    return (uint32_t)f32_to_bf16(lo) | ((uint32_t)f32_to_bf16(hi) << 16);
}
__device__ inline float bf_lo(uint32_t u) { return __uint_as_float(u << 16); }
__device__ inline float bf_hi(uint32_t u) { return __uint_as_float(u & 0xFFFF0000u); }
// {even col, odd col} of one packed dword — f32x2 so the backend can use v_pk_add_f32
__device__ inline f32x2 up2(uint32_t u) {
    f32x2 r;
    r.x = __uint_as_float(u << 16);
    r.y = __uint_as_float(u & 0xFFFF0000u);
    return r;
}

// ---------------- CSR build ----------------

__global__ void gnn_count_k(const int* __restrict__ edges, int* __restrict__ cnt, int E) {
    int t = blockIdx.x * 256 + threadIdx.x;
    if (t < E) atomicAdd(&cnt[edges[E + t]], 1);
}

__global__ void gnn_scan_block_k(const int* __restrict__ cnt, int* __restrict__ scanbuf,
                                 int* __restrict__ bsum, int n) {
    __shared__ int s[256];
    int i = blockIdx.x * 256 + threadIdx.x;
    int v = (i < n) ? (cnt[i] + 1) : 0;
    s[threadIdx.x] = v;
    __syncthreads();
    for (int off = 1; off < 256; off <<= 1) {
        int t = 0;
        if (threadIdx.x >= off) t = s[threadIdx.x - off];
        __syncthreads();
        if (threadIdx.x >= off) s[threadIdx.x] += t;
        __syncthreads();
    }
    if (i < n) scanbuf[i] = s[threadIdx.x];
    if (threadIdx.x == 255) bsum[blockIdx.x] = s[255];
}

// blocks [0,nbk): rowptr + pcur + dinv (bsum prefix re-reduced per block).
// blocks [nbk, nbk+16): W swizzle fp32 -> bf16 B-fragment order.
// Wsw[((ct*4+ks)*64+lane)*8+j] = bf16(W[(ks*32+(lane>>4)*8+j)*128 + ct*16+(lane&15)])
__global__ __launch_bounds__(256) void gnn_setup_k(const int* __restrict__ scanbuf,
                                                   const int* __restrict__ bsum,
                                                   const int* __restrict__ cnt,
                                                   int* __restrict__ rowptr,
                                                   int* __restrict__ pcur,
                                                   float* __restrict__ dinv,
                                                   const float* __restrict__ W1,
                                                   const float* __restrict__ W2,
                                                   uint16_t* __restrict__ w1s,
                                                   uint16_t* __restrict__ w2s,
                                                   int n, int nbk) {
    int b = blockIdx.x;
    if (b < nbk) {
        __shared__ int red[256];
        int t = threadIdx.x;
        int part = 0;
        for (int i = t; i < b; i += 256) part += bsum[i];
        red[t] = part;
        __syncthreads();
        for (int off = 128; off > 0; off >>= 1) {
            if (t < off) red[t] += red[t + off];
            __syncthreads();
        }
        int off0 = red[0];
        int i = b * 256 + t;
        if (i == 0) { rowptr[0] = 0; pcur[0] = 0; }
        if (i < n) {
            int v = scanbuf[i] + off0;
            rowptr[i + 1] = v;
            if (((i + 1) & 255) == 0) pcur[(i + 1) >> BSH] = v - (i + 1);
            dinv[i] = rsqrtf((float)(cnt[i] + 1));
        }
    } else {
        int wb = b - nbk;                      // 0..15
        const float* W = (wb < 8) ? W1 : W2;
        uint16_t* O = (wb < 8) ? w1s : w2s;
        int t = (wb & 7) * 256 + threadIdx.x;  // 0..2047
        int lane = t & 63;
        int ksct = t >> 6;                     // ct*4+ks
        int nn = (ksct >> 2) * 16 + (lane & 15);
        int k0 = (ksct & 3) * 32 + (lane >> 4) * 8;
        uint32_t d[4];
#pragma unroll
        for (int j = 0; j < 4; ++j)
            d[j] = pack_bf16x2(W[(size_t)(k0 + 2 * j) * HID + nn],
                               W[(size_t)(k0 + 2 * j + 1) * HID + nn]);
        *(uint4*)(O + (size_t)t * 8) = make_uint4(d[0], d[1], d[2], d[3]);
    }
}

__global__ __launch_bounds__(256) void gnn_bucket_scatter_k(const int* __restrict__ edges,
                                                            int* __restrict__ pcur,
                                                            uint32_t* __restrict__ pairbuf,
                                                            int E, int NB) {
    __shared__ int hist[NBMAX];
    int e0 = blockIdx.x * EPB;
    int e1 = min(E, e0 + EPB);
    for (int b = threadIdx.x; b < NB; b += 256) hist[b] = 0;
    __syncthreads();
    for (int e = e0 + threadIdx.x; e < e1; e += 256)
        atomicAdd(&hist[edges[E + e] >> BSH], 1);
    __syncthreads();
    for (int b = threadIdx.x; b < NB; b += 256) {
        int c = hist[b];
        hist[b] = (c > 0) ? atomicAdd(&pcur[b], c) : 0;
    }
    __syncthreads();
    for (int e = e0 + threadIdx.x; e < e1; e += 256) {
        int src = edges[e];
        int dst = edges[E + e];
        int pos = atomicAdd(&hist[dst >> BSH], 1);
        pairbuf[pos] = ((uint32_t)(dst & 255) << 24) | (uint32_t)src;
    }
}

__global__ __launch_bounds__(256) void gnn_build_csr_k(const uint32_t* __restrict__ pairbuf,
                                                       const int* __restrict__ rowptr,
                                                       int* __restrict__ colidx,
                                                       int* __restrict__ gcur, int n) {
    __shared__ int cur[256];
    __shared__ int colbuf[BCAP];
    int b = blockIdx.x;
    int nb0 = b << BSH;
    int nb1 = min(n, nb0 + 256);
    int nn = nb1 - nb0;
    int segbeg = rowptr[nb0];
    int segend = rowptr[nb1];
    int seglen = segend - segbeg;
    int pairbeg = segbeg - nb0;
    int npairs = (segend - nb1) - pairbeg;

    if (seglen <= BCAP) {
        if (threadIdx.x < nn) {
            int node = nb0 + threadIdx.x;
            int rel = rowptr[node] - segbeg;
            colbuf[rel] = node;            // self loop
            cur[threadIdx.x] = rel + 1;
        }
        __syncthreads();
        for (int p = threadIdx.x; p < npairs; p += 256) {
            uint32_t pr = pairbuf[pairbeg + p];
            int pos = atomicAdd(&cur[pr >> 24], 1);
            colbuf[pos] = (int)(pr & 0xFFFFFFu);
        }
        __syncthreads();
        for (int i = threadIdx.x; i < seglen; i += 256)
            colidx[segbeg + i] = colbuf[i];
    } else {
        if (threadIdx.x < nn) {
            int node = nb0 + threadIdx.x;
            colidx[rowptr[node]] = node;
        }
        __syncthreads();
        for (int p = threadIdx.x; p < npairs; p += 256) {
            uint32_t pr = pairbuf[pairbeg + p];
            int dst = nb0 + (int)(pr >> 24);
            int pos = atomicAdd(&gcur[dst], 1);
            colidx[rowptr[dst] + 1 + pos] = (int)(pr & 0xFFFFFFu);
        }
    }
}

// ---------------- MFMA GEMM [n,128] @ [128,128], row-scaled by dinv -> bf16 h' ----------------
// 256 threads = 4 waves x 16 rows. Per wave: 8 col-tiles x 4 K-steps of 16x16x32 bf16.
// Output is PANEL-MAJOR: outh[(col>>4)*n*16 + row*16 + (col&15)], panel = col tile ct.
// ABF16 path reads a panel-major bf16 A (aggregate output layout).

template <bool ABF16>
__global__ __launch_bounds__(256) void gnn_gemm_mfma_k(const void* __restrict__ Aptr,
                                                       const uint32_t* __restrict__ Wsw,
                                                       const float* __restrict__ dinv,
                                                       uint16_t* __restrict__ outh, int n) {
    int wave = threadIdx.x >> 6;
    int lane = threadIdx.x & 63;
    int m = lane & 15;
    int q = lane >> 4;
    int row0 = blockIdx.x * 64 + wave * 16;
    int arow = min(row0 + m, n - 1);
    const size_t n16 = (size_t)n * 16;

    f32x4 acc[8];
#pragma unroll
    for (int i = 0; i < 8; ++i) acc[i] = (f32x4){0.f, 0.f, 0.f, 0.f};

#pragma unroll
    for (int ks = 0; ks < 4; ++ks) {
        short8 a;
        if (ABF16) {
            // cols k0 = ks*32 + q*8 -> panel 2*ks + (q>>1), in-panel offset (q&1)*8
            const uint16_t* Ab = (const uint16_t*)Aptr;
            uint4 u = *(const uint4*)(Ab + (size_t)(2 * ks + (q >> 1)) * n16 +
                                      (size_t)arow * 16 + (q & 1) * 8);
            a = __builtin_bit_cast(short8, u);
        } else {
            const float* Af = (const float*)Aptr + (size_t)arow * HID + ks * 32 + q * 8;
            uint4 u0 = *(const uint4*)(Af);
            uint4 u1 = *(const uint4*)(Af + 4);
            uint4 p;
            p.x = pack_bf16x2(__uint_as_float(u0.x), __uint_as_float(u0.y));
            p.y = pack_bf16x2(__uint_as_float(u0.z), __uint_as_float(u0.w));
            p.z = pack_bf16x2(__uint_as_float(u1.x), __uint_as_float(u1.y));
            p.w = pack_bf16x2(__uint_as_float(u1.z), __uint_as_float(u1.w));
            a = __builtin_bit_cast(short8, p);
        }
#pragma unroll
        for (int ct = 0; ct < 8; ++ct) {
            uint4 bu = *(const uint4*)(Wsw + ((size_t)(ct * 4 + ks) * 64 + lane) * 4);
            short8 bfr = __builtin_bit_cast(short8, bu);
            acc[ct] = __builtin_amdgcn_mfma_f32_16x16x32_bf16(a, bfr, acc[ct], 0, 0, 0);
        }
    }

    float dv[4];
#pragma unroll
    for (int r = 0; r < 4; ++r) dv[r] = dinv[min(row0 + q * 4 + r, n - 1)];

#pragma unroll
    for (int ct = 0; ct < 8; ++ct) {
#pragma unroll
        for (int r = 0; r < 4; ++r) {
            int rr = row0 + q * 4 + r;
            if (rr < n)
                outh[(size_t)ct * n16 + (size_t)rr * 16 + m] = f32_to_bf16(acc[ct][r] * dv[r]);
        }
    }
}

// ---------------- aggregation: panel-partitioned, XCD-pinned ----------------
// grid = 8 * nchunks; panel = blockIdx&7 (-> XCD p via round-robin dispatch),
// chunk = blockIdx>>3. Block = 4 waves; wave = 4 nodes x 16 lanes.
// Per node: 8 edge slots x 2 lanes x 16 B = one 32 B panel row per edge.
// colidx / skip loads and output stores are non-temporal so the 3.2 MB panel
// slab stays resident in the XCD's 4 MB L2.

__global__ __launch_bounds__(256) void gnn_aggregate_panel_k(
    const uint16_t* __restrict__ hp,      // [8][n][16] bf16 panel-major
    const int* __restrict__ rowptr, const int* __restrict__ colidx,
    const float* __restrict__ dinv, const float* __restrict__ bias,
    const uint16_t* __restrict__ skipb,   // panel-major or null
    uint16_t* __restrict__ outp, int n) {
    const int panel = blockIdx.x & 7;
    const int chunk = blockIdx.x >> 3;
    const int lane = threadIdx.x & 63;
    const int grp = lane >> 4;
    const int sub = lane & 15;
    const int slot = sub >> 1;            // 0..7 edge slot
    const int hv = sub & 1;               // which 16B half of the 32B row chunk
    const int node = chunk * 16 + (threadIdx.x >> 6) * 4 + grp;
    if (node >= n) return;
    const size_t n16 = (size_t)n * 16;
    const uint4* __restrict__ hp4 = (const uint4*)(hp + (size_t)panel * n16);  // [n][2]

    const int beg = rowptr[node];
    const int end = rowptr[node + 1];

    f32x2 acc[4];
#pragma unroll
    for (int i = 0; i < 4; ++i) acc[i] = (f32x2){0.f, 0.f};

    int e = beg;
    for (; e + 16 <= end; e += 16) {
        int j0 = __builtin_nontemporal_load(colidx + e + slot);
        int j1 = __builtin_nontemporal_load(colidx + e + 8 + slot);
        uint4 u0 = hp4[(size_t)j0 * 2 + hv];
        uint4 u1 = hp4[(size_t)j1 * 2 + hv];
        acc[0] += up2(u0.x); acc[1] += up2(u0.y); acc[2] += up2(u0.z); acc[3] += up2(u0.w);
        acc[0] += up2(u1.x); acc[1] += up2(u1.y); acc[2] += up2(u1.z); acc[3] += up2(u1.w);
    }
    if (e + 8 <= end) {
        int j = __builtin_nontemporal_load(colidx + e + slot);
        uint4 u = hp4[(size_t)j * 2 + hv];
        acc[0] += up2(u.x); acc[1] += up2(u.y); acc[2] += up2(u.z); acc[3] += up2(u.w);
        e += 8;
    }
    if (slot < end - e) {
        int j = __builtin_nontemporal_load(colidx + e + slot);
        uint4 u = hp4[(size_t)j * 2 + hv];
        acc[0] += up2(u.x); acc[1] += up2(u.y); acc[2] += up2(u.z); acc[3] += up2(u.w);
    }

    float a8[8];
#pragma unroll
    for (int i = 0; i < 4; ++i) { a8[2 * i] = acc[i].x; a8[2 * i + 1] = acc[i].y; }
    // reduce over 8 slots (lane bits 1..3); partners always share node and hv
#pragma unroll
    for (int k = 0; k < 8; ++k) {
        a8[k] += __shfl_xor(a8[k], 2, 64);
        a8[k] += __shfl_xor(a8[k], 4, 64);
        a8[k] += __shfl_xor(a8[k], 8, 64);
    }

    if (sub < 2) {                        // lanes hv=0,1 of slot 0 hold the sums
        const size_t off = (size_t)panel * n16 + (size_t)node * 16 + hv * 8;
        float di = dinv[node];
        const float* bp = bias + panel * 16 + hv * 8;
        float4 b0 = *(const float4*)bp;
        float4 b1 = *(const float4*)(bp + 4);
        float o[8];
        o[0] = fmaxf(di * a8[0] + b0.x, 0.0f);
        o[1] = fmaxf(di * a8[1] + b0.y, 0.0f);
        o[2] = fmaxf(di * a8[2] + b0.z, 0.0f);
        o[3] = fmaxf(di * a8[3] + b0.w, 0.0f);
        o[4] = fmaxf(di * a8[4] + b1.x, 0.0f);
        o[5] = fmaxf(di * a8[5] + b1.y, 0.0f);
        o[6] = fmaxf(di * a8[6] + b1.z, 0.0f);
        o[7] = fmaxf(di * a8[7] + b1.w, 0.0f);
        if (skipb) {
            u32x4 sv = __builtin_nontemporal_load((const u32x4*)(skipb + off));
            o[0] += bf_lo(sv[0]); o[1] += bf_hi(sv[0]);
            o[2] += bf_lo(sv[1]); o[3] += bf_hi(sv[1]);
            o[4] += bf_lo(sv[2]); o[5] += bf_hi(sv[2]);
            o[6] += bf_lo(sv[3]); o[7] += bf_hi(sv[3]);
        }
        u32x4 pv;
        pv[0] = pack_bf16x2(o[0], o[1]);
        pv[1] = pack_bf16x2(o[2], o[3]);
        pv[2] = pack_bf16x2(o[4], o[5]);
        pv[3] = pack_bf16x2(o[6], o[7]);
        __builtin_nontemporal_store(pv, (u32x4*)(outp + off));
    }
}

// ---------------- final: bf16 sum[8][n][16] (panel-major) @ Wc[128,40] + bc -> fp32 ----------------

__global__ __launch_bounds__(320) void gnn_final_k(const uint16_t* __restrict__ sumh,
                                                   const float* __restrict__ wc,
                                                   const float* __restrict__ bc,
                                                   float* __restrict__ out, int n) {
    __shared__ float a[64 * HID];  // 32 KB, float4 block (r, c4) at r*32 + (c4 ^ (r&7))
    const int tx = threadIdx.x % 10;
    const int ty = threadIdx.x / 10;
    const int row0 = blockIdx.x * 64;

    {
        const uint4* S8 = (const uint4*)sumh;  // panel-major: [8][n][2] uint4
        const size_t pstride = (size_t)n * 2;
        float4* s4 = (float4*)a;
        for (int idx = threadIdx.x; idx < 64 * 16; idx += 320) {
            int r = idx >> 4, c8 = idx & 15;
            uint4 v = make_uint4(0u, 0u, 0u, 0u);
            if (row0 + r < n)
                v = S8[(size_t)(c8 >> 1) * pstride + (size_t)(row0 + r) * 2 + (c8 & 1)];
            float4 f0 = make_float4(bf_lo(v.x), bf_hi(v.x), bf_lo(v.y), bf_hi(v.y));
            float4 f1 = make_float4(bf_lo(v.z), bf_hi(v.z), bf_lo(v.w), bf_hi(v.w));
            s4[r * 32 + ((2 * c8) ^ (r & 7))] = f0;
            s4[r * 32 + ((2 * c8 + 1) ^ (r & 7))] = f1;
        }
    }
    __syncthreads();

    float acc[2][4];
    {
        float b0 = bc[tx * 4], b1 = bc[tx * 4 + 1], b2 = bc[tx * 4 + 2], b3 = bc[tx * 4 + 3];
        acc[0][0] = b0; acc[0][1] = b1; acc[0][2] = b2; acc[0][3] = b3;
        acc[1][0] = b0; acc[1][1] = b1; acc[1][2] = b2; acc[1][3] = b3;
    }
    const float* wp = wc + tx * 4;
    const float4* s4 = (const float4*)a;

#pragma unroll 2
    for (int k = 0; k < HID; k += 4) {
        int c4 = k >> 2;
        float ar[2][4];
#pragma unroll
        for (int r = 0; r < 2; ++r) {
            int row = ty * 2 + r;
            *(float4*)&ar[r][0] = s4[row * 32 + (c4 ^ (row & 7))];
        }
#pragma unroll
        for (int kk = 0; kk < 4; ++kk) {
            float4 w = *(const float4*)(wp + (size_t)(k + kk) * OUTD);
#pragma unroll
            for (int r = 0; r < 2; ++r) {
                acc[r][0] += ar[r][kk] * w.x;
                acc[r][1] += ar[r][kk] * w.y;
                acc[r][2] += ar[r][kk] * w.z;
                acc[r][3] += ar[r][kk] * w.w;
            }
        }
    }

#pragma unroll
    for (int r = 0; r < 2; ++r) {
        int row = row0 + ty * 2 + r;
        if (row < n) {
            float4 v = make_float4(acc[r][0], acc[r][1], acc[r][2], acc[r][3]);
            *(float4*)(out + (size_t)row * OUTD + tx * 4) = v;
        }
    }
}

// ---------------- launch ----------------

extern "C" void kernel_launch(void* const* d_in, const int* in_sizes, int n_in,
                              void* d_out, int out_size, void* d_ws, size_t ws_size,
                              hipStream_t stream) {
    const int N = in_sizes[0] / HID;   // 100000
    const int E = in_sizes[7] / 2;     // 1600000

    const float* x  = (const float*)d_in[0];
    const float* W1 = (const float*)d_in[1];
    const float* b1 = (const float*)d_in[2];
    const float* W2 = (const float*)d_in[3];
    const float* b2 = (const float*)d_in[4];
    const float* Wc = (const float*)d_in[5];
    const float* bc = (const float*)d_in[6];
    const int* edges = (const int*)d_in[7];
    float* out = (float*)d_out;

    // workspace carve-up (256B aligned), ~66 MB total
    char* w = (char*)d_ws;
    auto alloc = [&](size_t bytes) -> char* {
        char* p = w;
        w += (bytes + 255) & ~(size_t)255;
        return p;
    };
    uint16_t* hbuf  = (uint16_t*)alloc((size_t)N * HID * 2);  // h' bf16 panel-major
    uint16_t* bufBh = (uint16_t*)alloc((size_t)N * HID * 2);  // bf16 out1, then bf16 sum (panel-major)
    int*   cnt     = (int*)alloc((size_t)N * 4);
    int*   gcur    = (int*)alloc((size_t)N * 4);
    int*   rowptr  = (int*)alloc((size_t)(N + 1) * 4);
    int*   scanbuf = (int*)alloc((size_t)N * 4);
    int*   bsum    = (int*)alloc(512 * 4);
    int*   pcur    = (int*)alloc(512 * 4);
    int*   colidx  = (int*)alloc((size_t)(E + N) * 4);
    float* dinv    = (float*)alloc((size_t)N * 4);
    uint32_t* pairbuf = (uint32_t*)alloc((size_t)E * 4);
    uint16_t* w1s  = (uint16_t*)alloc(HID * HID * 2);
    uint16_t* w2s  = (uint16_t*)alloc(HID * HID * 2);

    const int nb1 = (N + 255) / 256;   // scan blocks (391)
    const int NB  = (N + 255) >> BSH;  // buckets (391)

    size_t cntspan = (size_t)((char*)rowptr - (char*)cnt);
    hipMemsetAsync(cnt, 0, cntspan, stream);

    gnn_count_k<<<(E + 255) / 256, 256, 0, stream>>>(edges, cnt, E);
    gnn_scan_block_k<<<nb1, 256, 0, stream>>>(cnt, scanbuf, bsum, N);
    gnn_setup_k<<<nb1 + 16, 256, 0, stream>>>(scanbuf, bsum, cnt, rowptr, pcur, dinv,
                                              W1, W2, w1s, w2s, N, nb1);
    gnn_bucket_scatter_k<<<(E + EPB - 1) / EPB, 256, 0, stream>>>(edges, pcur, pairbuf, E, NB);
    gnn_build_csr_k<<<NB, 256, 0, stream>>>(pairbuf, rowptr, colidx, gcur, N);

    const int aggBlocks = ((N + 15) / 16) * 8;   // 8 panels, XCD-pinned via blockIdx&7

    // layer 1: h1' = bf16(dinv * (x @ W1)) ; bufBh = bf16(relu(dinv*agg(h1') + b1))
    gnn_gemm_mfma_k<false><<<(N + 63) / 64, 256, 0, stream>>>(x, (const uint32_t*)w1s, dinv, hbuf, N);
    gnn_aggregate_panel_k<<<aggBlocks, 256, 0, stream>>>(hbuf, rowptr, colidx,
                                                         dinv, b1, nullptr, bufBh, N);
    // layer 2: h2' = bf16(dinv * (out1 @ W2)) ; bufBh = bf16(relu(...) + out1) in place
    gnn_gemm_mfma_k<true><<<(N + 63) / 64, 256, 0, stream>>>(bufBh, (const uint32_t*)w2s, dinv, hbuf, N);
    gnn_aggregate_panel_k<<<aggBlocks, 256, 0, stream>>>(hbuf, rowptr, colidx,
                                                         dinv, b2, bufBh, bufBh, N);
    // head
    gnn_final_k<<<(N + 63) / 64, 320, 0, stream>>>(bufBh, Wc, bc, out, N);
}

// Round 2
// 535.833 us; speedup vs baseline: 1.0469x; 1.0469x over previous
//
#include <hip/hip_runtime.h>
#include <stdint.h>

// GNN: 2-layer GCN + skip + classifier head. All fp32 in/out; edge_index int32.
// N=100000, E=1600000, F=H=128, OUT=40.
//
// Round-12: panel-partitioned aggregation, instruction-efficient rewrite.
// h' stored PANEL-MAJOR [8][N+1][16] bf16 (32 B/row/panel, 3.2 MB slab, row N = zeros).
// Aggregate blocks pin panel p to XCD p via blockIdx&7 (round-1 PROVED fetch 203->62 MB).
// Round-11 failure was VALU/latency bloat, not fetch: this version uses 32-bit voffset
// gathers off an SGPR base, zero-row clamp instead of branches, 8 lanes/node
// (4 slots x 2 hv) with 2-hop reduce, 1-deep colidx prefetch, early epilogue loads.

#define HID 128
#define OUTD 40
#define BSH 8                 // 256 nodes per bucket
#define BCAP 6144             // LDS colbuf entries per bucket (mean ~4350)
#define EPB 8192              // edges per scatter block
#define NBMAX 512

typedef __attribute__((ext_vector_type(8))) short short8;
typedef __attribute__((ext_vector_type(4))) float f32x4;
typedef __attribute__((ext_vector_type(2))) float f32x2;
typedef __attribute__((ext_vector_type(4))) unsigned int u32x4;

__device__ inline uint16_t f32_to_bf16(float f) {
    uint32_t u = __float_as_uint(f);
    uint32_t r = u + 0x7FFFu + ((u >> 16) & 1u);
    return (uint16_t)(r >> 16);
}
__device__ inline uint32_t pack_bf16x2(float lo, float hi) {
    return (uint32_t)f32_to_bf16(lo) | ((uint32_t)f32_to_bf16(hi) << 16);
}
__device__ inline float bf_lo(uint32_t u) { return __uint_as_float(u << 16); }
__device__ inline float bf_hi(uint32_t u) { return __uint_as_float(u & 0xFFFF0000u); }
// {even col, odd col} of one packed dword — f32x2 so the backend can use v_pk_add_f32
__device__ inline f32x2 up2(uint32_t u) {
    f32x2 r;
    r.x = __uint_as_float(u << 16);
    r.y = __uint_as_float(u & 0xFFFF0000u);
    return r;
}

// ---------------- CSR build ----------------

__global__ void gnn_count_k(const int* __restrict__ edges, int* __restrict__ cnt, int E) {
    int t = blockIdx.x * 256 + threadIdx.x;
    if (t < E) atomicAdd(&cnt[edges[E + t]], 1);
}

__global__ void gnn_scan_block_k(const int* __restrict__ cnt, int* __restrict__ scanbuf,
                                 int* __restrict__ bsum, int n) {
    __shared__ int s[256];
    int i = blockIdx.x * 256 + threadIdx.x;
    int v = (i < n) ? (cnt[i] + 1) : 0;
    s[threadIdx.x] = v;
    __syncthreads();
    for (int off = 1; off < 256; off <<= 1) {
        int t = 0;
        if (threadIdx.x >= off) t = s[threadIdx.x - off];
        __syncthreads();
        if (threadIdx.x >= off) s[threadIdx.x] += t;
        __syncthreads();
    }
    if (i < n) scanbuf[i] = s[threadIdx.x];
    if (threadIdx.x == 255) bsum[blockIdx.x] = s[255];
}

// blocks [0,nbk): rowptr + pcur + dinv (bsum prefix re-reduced per block).
// blocks [nbk, nbk+16): W swizzle fp32 -> bf16 B-fragment order.
// block nbk+16: zero-row init for hbuf (row n of each panel).
__global__ __launch_bounds__(256) void gnn_setup_k(const int* __restrict__ scanbuf,
                                                   const int* __restrict__ bsum,
                                                   const int* __restrict__ cnt,
                                                   int* __restrict__ rowptr,
                                                   int* __restrict__ pcur,
                                                   float* __restrict__ dinv,
                                                   const float* __restrict__ W1,
                                                   const float* __restrict__ W2,
                                                   uint16_t* __restrict__ w1s,
                                                   uint16_t* __restrict__ w2s,
                                                   uint16_t* __restrict__ hbuf,
                                                   int n, int nbk) {
    int b = blockIdx.x;
    if (b < nbk) {
        __shared__ int red[256];
        int t = threadIdx.x;
        int part = 0;
        for (int i = t; i < b; i += 256) part += bsum[i];
        red[t] = part;
        __syncthreads();
        for (int off = 128; off > 0; off >>= 1) {
            if (t < off) red[t] += red[t + off];
            __syncthreads();
        }
        int off0 = red[0];
        int i = b * 256 + t;
        if (i == 0) { rowptr[0] = 0; pcur[0] = 0; }
        if (i < n) {
            int v = scanbuf[i] + off0;
            rowptr[i + 1] = v;
            if (((i + 1) & 255) == 0) pcur[(i + 1) >> BSH] = v - (i + 1);
            dinv[i] = rsqrtf((float)(cnt[i] + 1));
        }
    } else if (b < nbk + 16) {
        int wb = b - nbk;                      // 0..15
        const float* W = (wb < 8) ? W1 : W2;
        uint16_t* O = (wb < 8) ? w1s : w2s;
        int t = (wb & 7) * 256 + threadIdx.x;  // 0..2047
        int lane = t & 63;
        int ksct = t >> 6;                     // ct*4+ks
        int nn = (ksct >> 2) * 16 + (lane & 15);
        int k0 = (ksct & 3) * 32 + (lane >> 4) * 8;
        uint32_t d[4];
#pragma unroll
        for (int j = 0; j < 4; ++j)
            d[j] = pack_bf16x2(W[(size_t)(k0 + 2 * j) * HID + nn],
                               W[(size_t)(k0 + 2 * j + 1) * HID + nn]);
        *(uint4*)(O + (size_t)t * 8) = make_uint4(d[0], d[1], d[2], d[3]);
    } else {
        // zero rows: hbuf[panel][n][0..15] = 0 for all 8 panels
        if (threadIdx.x < 128) {
            int panel = threadIdx.x >> 4;
            int col = threadIdx.x & 15;
            size_t p16 = (size_t)(n + 1) * 16;
            hbuf[(size_t)panel * p16 + (size_t)n * 16 + col] = 0;
        }
    }
}

__global__ __launch_bounds__(256) void gnn_bucket_scatter_k(const int* __restrict__ edges,
                                                            int* __restrict__ pcur,
                                                            uint32_t* __restrict__ pairbuf,
                                                            int E, int NB) {
    __shared__ int hist[NBMAX];
    int e0 = blockIdx.x * EPB;
    int e1 = min(E, e0 + EPB);
    for (int b = threadIdx.x; b < NB; b += 256) hist[b] = 0;
    __syncthreads();
    for (int e = e0 + threadIdx.x; e < e1; e += 256)
        atomicAdd(&hist[edges[E + e] >> BSH], 1);
    __syncthreads();
    for (int b = threadIdx.x; b < NB; b += 256) {
        int c = hist[b];
        hist[b] = (c > 0) ? atomicAdd(&pcur[b], c) : 0;
    }
    __syncthreads();
    for (int e = e0 + threadIdx.x; e < e1; e += 256) {
        int src = edges[e];
        int dst = edges[E + e];
        int pos = atomicAdd(&hist[dst >> BSH], 1);
        pairbuf[pos] = ((uint32_t)(dst & 255) << 24) | (uint32_t)src;
    }
}

__global__ __launch_bounds__(256) void gnn_build_csr_k(const uint32_t* __restrict__ pairbuf,
                                                       const int* __restrict__ rowptr,
                                                       int* __restrict__ colidx,
                                                       int* __restrict__ gcur, int n) {
    __shared__ int cur[256];
    __shared__ int colbuf[BCAP];
    int b = blockIdx.x;
    int nb0 = b << BSH;
    int nb1 = min(n, nb0 + 256);
    int nn = nb1 - nb0;
    int segbeg = rowptr[nb0];
    int segend = rowptr[nb1];
    int seglen = segend - segbeg;
    int pairbeg = segbeg - nb0;
    int npairs = (segend - nb1) - pairbeg;

    if (seglen <= BCAP) {
        if (threadIdx.x < nn) {
            int node = nb0 + threadIdx.x;
            int rel = rowptr[node] - segbeg;
            colbuf[rel] = node;            // self loop
            cur[threadIdx.x] = rel + 1;
        }
        __syncthreads();
        for (int p = threadIdx.x; p < npairs; p += 256) {
            uint32_t pr = pairbuf[pairbeg + p];
            int pos = atomicAdd(&cur[pr >> 24], 1);
            colbuf[pos] = (int)(pr & 0xFFFFFFu);
        }
        __syncthreads();
        for (int i = threadIdx.x; i < seglen; i += 256)
            colidx[segbeg + i] = colbuf[i];
    } else {
        if (threadIdx.x < nn) {
            int node = nb0 + threadIdx.x;
            colidx[rowptr[node]] = node;
        }
        __syncthreads();
        for (int p = threadIdx.x; p < npairs; p += 256) {
            uint32_t pr = pairbuf[pairbeg + p];
            int dst = nb0 + (int)(pr >> 24);
            int pos = atomicAdd(&gcur[dst], 1);
            colidx[rowptr[dst] + 1 + pos] = (int)(pr & 0xFFFFFFu);
        }
    }
}

// ---------------- MFMA GEMM [n,128] @ [128,128], row-scaled by dinv -> bf16 h' ----------------
// 256 threads = 4 waves x 16 rows. Per wave: 8 col-tiles x 4 K-steps of 16x16x32 bf16.
// Output PANEL-MAJOR: outh[(col>>4)*p16 + row*16 + (col&15)], p16 = (n+1)*16.
// ABF16 path reads panel-major bf16 A (aggregate output layout, same stride).

template <bool ABF16>
__global__ __launch_bounds__(256) void gnn_gemm_mfma_k(const void* __restrict__ Aptr,
                                                       const uint32_t* __restrict__ Wsw,
                                                       const float* __restrict__ dinv,
                                                       uint16_t* __restrict__ outh,
                                                       int n, int p16) {
    int wave = threadIdx.x >> 6;
    int lane = threadIdx.x & 63;
    int m = lane & 15;
    int q = lane >> 4;
    int row0 = blockIdx.x * 64 + wave * 16;
    int arow = min(row0 + m, n - 1);
    const size_t P16 = (size_t)p16;

    f32x4 acc[8];
#pragma unroll
    for (int i = 0; i < 8; ++i) acc[i] = (f32x4){0.f, 0.f, 0.f, 0.f};

#pragma unroll
    for (int ks = 0; ks < 4; ++ks) {
        short8 a;
        if (ABF16) {
            // cols k0 = ks*32 + q*8 -> panel 2*ks + (q>>1), in-panel offset (q&1)*8
            const uint16_t* Ab = (const uint16_t*)Aptr;
            uint4 u = *(const uint4*)(Ab + (size_t)(2 * ks + (q >> 1)) * P16 +
                                      (size_t)arow * 16 + (q & 1) * 8);
            a = __builtin_bit_cast(short8, u);
        } else {
            const float* Af = (const float*)Aptr + (size_t)arow * HID + ks * 32 + q * 8;
            uint4 u0 = *(const uint4*)(Af);
            uint4 u1 = *(const uint4*)(Af + 4);
            uint4 p;
            p.x = pack_bf16x2(__uint_as_float(u0.x), __uint_as_float(u0.y));
            p.y = pack_bf16x2(__uint_as_float(u0.z), __uint_as_float(u0.w));
            p.z = pack_bf16x2(__uint_as_float(u1.x), __uint_as_float(u1.y));
            p.w = pack_bf16x2(__uint_as_float(u1.z), __uint_as_float(u1.w));
            a = __builtin_bit_cast(short8, p);
        }
#pragma unroll
        for (int ct = 0; ct < 8; ++ct) {
            uint4 bu = *(const uint4*)(Wsw + ((size_t)(ct * 4 + ks) * 64 + lane) * 4);
            short8 bfr = __builtin_bit_cast(short8, bu);
            acc[ct] = __builtin_amdgcn_mfma_f32_16x16x32_bf16(a, bfr, acc[ct], 0, 0, 0);
        }
    }

    float dv[4];
#pragma unroll
    for (int r = 0; r < 4; ++r) dv[r] = dinv[min(row0 + q * 4 + r, n - 1)];

#pragma unroll
    for (int ct = 0; ct < 8; ++ct) {
#pragma unroll
        for (int r = 0; r < 4; ++r) {
            int rr = row0 + q * 4 + r;
            if (rr < n)
                outh[(size_t)ct * P16 + (size_t)rr * 16 + m] = f32_to_bf16(acc[ct][r] * dv[r]);
        }
    }
}

// ---------------- aggregation: panel-partitioned, XCD-pinned, low-overhead ----------------
// grid = 8 * ceil(N/32); panel = blockIdx&7 (-> XCD p), chunk = blockIdx>>3.
// Block = 4 waves; wave = 8 nodes x (4 slots x 2 hv). Per chunk of 8 edges:
// slot s covers edges e+s and e+4+s; out-of-range slots clamp j -> n (zero row).
// Gather: 32-bit voffset (j<<5 | hv<<4) off SGPR panel base. colidx nt-loaded with
// 1-deep prefetch; epilogue loads (dinv/bias/skip) issued before the 2-hop reduce.

__global__ __launch_bounds__(256) void gnn_aggregate_panel_k(
    const uint16_t* __restrict__ hp,      // [8][n+1][16] bf16 panel-major; row n = zeros
    const int* __restrict__ rowptr, const int* __restrict__ colidx,
    const float* __restrict__ dinv, const float* __restrict__ bias,
    const uint16_t* __restrict__ skipb,   // panel-major (same stride) or null
    uint16_t* __restrict__ outp, int n, int p16) {
    const int panel = blockIdx.x & 7;
    const int lane = threadIdx.x & 63;
    const int wave = threadIdx.x >> 6;
    const int grp = lane >> 3;            // node within wave
    const int slot = (lane >> 1) & 3;     // 0..3
    const int hv = lane & 1;              // 16B half of the 32B row
    int node = (blockIdx.x >> 3) * 32 + wave * 8 + grp;
    const bool nodeOK = node < n;
    if (!nodeOK) node = n - 1;

    const char* __restrict__ hpB = (const char*)(hp + (size_t)panel * p16);
    const uint32_t hvo = (uint32_t)hv << 4;

    const int beg = rowptr[node];
    const int end = rowptr[node + 1];

    f32x2 acc[4];
#pragma unroll
    for (int i = 0; i < 4; ++i) acc[i] = (f32x2){0.f, 0.f};

    int e = beg;
    int j0 = __builtin_nontemporal_load(colidx + e + slot);
    int j1 = __builtin_nontemporal_load(colidx + e + 4 + slot);
    while (true) {
        const int e2 = e + 8;
        const bool more = e2 < end;
        const int k0 = (e + slot < end) ? j0 : n;       // clamp to zero row
        const int k1 = (e + 4 + slot < end) ? j1 : n;
        if (more) {
            j0 = __builtin_nontemporal_load(colidx + e2 + slot);
            j1 = __builtin_nontemporal_load(colidx + e2 + 4 + slot);
        }
        const uint4 u0 = *(const uint4*)(hpB + (((uint32_t)k0 << 5) | hvo));
        const uint4 u1 = *(const uint4*)(hpB + (((uint32_t)k1 << 5) | hvo));
        acc[0] += up2(u0.x); acc[1] += up2(u0.y); acc[2] += up2(u0.z); acc[3] += up2(u0.w);
        acc[0] += up2(u1.x); acc[1] += up2(u1.y); acc[2] += up2(u1.z); acc[3] += up2(u1.w);
        if (!more) break;
        e = e2;
    }

    // epilogue loads issued before the reduce (hide latency under shfl chain)
    const size_t off16 = (size_t)panel * p16 + (size_t)node * 16 + hv * 8;
    float di = 0.f;
    float4 b0 = make_float4(0.f, 0.f, 0.f, 0.f), b1 = b0;
    u32x4 sv = (u32x4){0u, 0u, 0u, 0u};
    if (slot == 0) {
        di = dinv[node];
        const float* bp = bias + panel * 16 + hv * 8;
        b0 = *(const float4*)bp;
        b1 = *(const float4*)(bp + 4);
        if (skipb) sv = __builtin_nontemporal_load((const u32x4*)(skipb + off16));
    }

    float a8[8];
#pragma unroll
    for (int i = 0; i < 4; ++i) { a8[2 * i] = acc[i].x; a8[2 * i + 1] = acc[i].y; }
#pragma unroll
    for (int k = 0; k < 8; ++k) {
        a8[k] += __shfl_xor(a8[k], 2, 64);
        a8[k] += __shfl_xor(a8[k], 4, 64);
    }

    if (slot == 0 && nodeOK) {
        float o[8];
        o[0] = fmaxf(di * a8[0] + b0.x, 0.f);
        o[1] = fmaxf(di * a8[1] + b0.y, 0.f);
        o[2] = fmaxf(di * a8[2] + b0.z, 0.f);
        o[3] = fmaxf(di * a8[3] + b0.w, 0.f);
        o[4] = fmaxf(di * a8[4] + b1.x, 0.f);
        o[5] = fmaxf(di * a8[5] + b1.y, 0.f);
        o[6] = fmaxf(di * a8[6] + b1.z, 0.f);
        o[7] = fmaxf(di * a8[7] + b1.w, 0.f);
        if (skipb) {
            o[0] += bf_lo(sv[0]); o[1] += bf_hi(sv[0]);
            o[2] += bf_lo(sv[1]); o[3] += bf_hi(sv[1]);
            o[4] += bf_lo(sv[2]); o[5] += bf_hi(sv[2]);
            o[6] += bf_lo(sv[3]); o[7] += bf_hi(sv[3]);
        }
        u32x4 pv;
        pv[0] = pack_bf16x2(o[0], o[1]);
        pv[1] = pack_bf16x2(o[2], o[3]);
        pv[2] = pack_bf16x2(o[4], o[5]);
        pv[3] = pack_bf16x2(o[6], o[7]);
        __builtin_nontemporal_store(pv, (u32x4*)(outp + off16));
    }
}

// ---------------- final: bf16 sum[8][n+1][16] (panel-major) @ Wc[128,40] + bc -> fp32 ----------------

__global__ __launch_bounds__(320) void gnn_final_k(const uint16_t* __restrict__ sumh,
                                                   const float* __restrict__ wc,
                                                   const float* __restrict__ bc,
                                                   float* __restrict__ out, int n, int ps4) {
    __shared__ float a[64 * HID];  // 32 KB, float4 block (r, c4) at r*32 + (c4 ^ (r&7))
    const int tx = threadIdx.x % 10;
    const int ty = threadIdx.x / 10;
    const int row0 = blockIdx.x * 64;

    {
        const uint4* S8 = (const uint4*)sumh;  // panel-major: [8][(n+1)][2] uint4
        const size_t pstride = (size_t)ps4;
        float4* s4 = (float4*)a;
        for (int idx = threadIdx.x; idx < 64 * 16; idx += 320) {
            int r = idx >> 4, c8 = idx & 15;
            uint4 v = make_uint4(0u, 0u, 0u, 0u);
            if (row0 + r < n)
                v = S8[(size_t)(c8 >> 1) * pstride + (size_t)(row0 + r) * 2 + (c8 & 1)];
            float4 f0 = make_float4(bf_lo(v.x), bf_hi(v.x), bf_lo(v.y), bf_hi(v.y));
            float4 f1 = make_float4(bf_lo(v.z), bf_hi(v.z), bf_lo(v.w), bf_hi(v.w));
            s4[r * 32 + ((2 * c8) ^ (r & 7))] = f0;
            s4[r * 32 + ((2 * c8 + 1) ^ (r & 7))] = f1;
        }
    }
    __syncthreads();

    float acc[2][4];
    {
        float b0 = bc[tx * 4], b1 = bc[tx * 4 + 1], b2 = bc[tx * 4 + 2], b3 = bc[tx * 4 + 3];
        acc[0][0] = b0; acc[0][1] = b1; acc[0][2] = b2; acc[0][3] = b3;
        acc[1][0] = b0; acc[1][1] = b1; acc[1][2] = b2; acc[1][3] = b3;
    }
    const float* wp = wc + tx * 4;
    const float4* s4 = (const float4*)a;

#pragma unroll 2
    for (int k = 0; k < HID; k += 4) {
        int c4 = k >> 2;
        float ar[2][4];
#pragma unroll
        for (int r = 0; r < 2; ++r) {
            int row = ty * 2 + r;
            *(float4*)&ar[r][0] = s4[row * 32 + (c4 ^ (row & 7))];
        }
#pragma unroll
        for (int kk = 0; kk < 4; ++kk) {
            float4 w = *(const float4*)(wp + (size_t)(k + kk) * OUTD);
#pragma unroll
            for (int r = 0; r < 2; ++r) {
                acc[r][0] += ar[r][kk] * w.x;
                acc[r][1] += ar[r][kk] * w.y;
                acc[r][2] += ar[r][kk] * w.z;
                acc[r][3] += ar[r][kk] * w.w;
            }
        }
    }

#pragma unroll
    for (int r = 0; r < 2; ++r) {
        int row = row0 + ty * 2 + r;
        if (row < n) {
            float4 v = make_float4(acc[r][0], acc[r][1], acc[r][2], acc[r][3]);
            *(float4*)(out + (size_t)row * OUTD + tx * 4) = v;
        }
    }
}

// ---------------- launch ----------------

extern "C" void kernel_launch(void* const* d_in, const int* in_sizes, int n_in,
                              void* d_out, int out_size, void* d_ws, size_t ws_size,
                              hipStream_t stream) {
    const int N = in_sizes[0] / HID;   // 100000
    const int E = in_sizes[7] / 2;     // 1600000

    const float* x  = (const float*)d_in[0];
    const float* W1 = (const float*)d_in[1];
    const float* b1 = (const float*)d_in[2];
    const float* W2 = (const float*)d_in[3];
    const float* b2 = (const float*)d_in[4];
    const float* Wc = (const float*)d_in[5];
    const float* bc = (const float*)d_in[6];
    const int* edges = (const int*)d_in[7];
    float* out = (float*)d_out;

    const int P16 = (N + 1) * 16;      // panel stride, uint16 units

    // workspace carve-up (256B aligned), ~66 MB total
    char* w = (char*)d_ws;
    auto alloc = [&](size_t bytes) -> char* {
        char* p = w;
        w += (bytes + 255) & ~(size_t)255;
        return p;
    };
    uint16_t* hbuf  = (uint16_t*)alloc((size_t)(N + 1) * HID * 2);  // h' bf16 panel-major + zero row
    uint16_t* bufBh = (uint16_t*)alloc((size_t)(N + 1) * HID * 2);  // bf16 out1, then bf16 sum
    int*   cnt     = (int*)alloc((size_t)N * 4);
    int*   gcur    = (int*)alloc((size_t)N * 4);
    int*   rowptr  = (int*)alloc((size_t)(N + 1) * 4);
    int*   scanbuf = (int*)alloc((size_t)N * 4);
    int*   bsum    = (int*)alloc(512 * 4);
    int*   pcur    = (int*)alloc(512 * 4);
    int*   colidx  = (int*)alloc((size_t)(E + N) * 4);
    float* dinv    = (float*)alloc((size_t)N * 4);
    uint32_t* pairbuf = (uint32_t*)alloc((size_t)E * 4);
    uint16_t* w1s  = (uint16_t*)alloc(HID * HID * 2);
    uint16_t* w2s  = (uint16_t*)alloc(HID * HID * 2);

    const int nb1 = (N + 255) / 256;   // scan blocks (391)
    const int NB  = (N + 255) >> BSH;  // buckets (391)

    size_t cntspan = (size_t)((char*)rowptr - (char*)cnt);
    hipMemsetAsync(cnt, 0, cntspan, stream);

    gnn_count_k<<<(E + 255) / 256, 256, 0, stream>>>(edges, cnt, E);
    gnn_scan_block_k<<<nb1, 256, 0, stream>>>(cnt, scanbuf, bsum, N);
    gnn_setup_k<<<nb1 + 17, 256, 0, stream>>>(scanbuf, bsum, cnt, rowptr, pcur, dinv,
                                              W1, W2, w1s, w2s, hbuf, N, nb1);
    gnn_bucket_scatter_k<<<(E + EPB - 1) / EPB, 256, 0, stream>>>(edges, pcur, pairbuf, E, NB);
    gnn_build_csr_k<<<NB, 256, 0, stream>>>(pairbuf, rowptr, colidx, gcur, N);

    const int aggBlocks = ((N + 31) / 32) * 8;   // 8 panels, XCD-pinned via blockIdx&7

    // layer 1: h1' = bf16(dinv * (x @ W1)) ; bufBh = bf16(relu(dinv*agg(h1') + b1))
    gnn_gemm_mfma_k<false><<<(N + 63) / 64, 256, 0, stream>>>(x, (const uint32_t*)w1s, dinv,
                                                              hbuf, N, P16);
    gnn_aggregate_panel_k<<<aggBlocks, 256, 0, stream>>>(hbuf, rowptr, colidx,
                                                         dinv, b1, nullptr, bufBh, N, P16);
    // layer 2: h2' = bf16(dinv * (out1 @ W2)) ; bufBh = bf16(relu(...) + out1) in place
    gnn_gemm_mfma_k<true><<<(N + 63) / 64, 256, 0, stream>>>(bufBh, (const uint32_t*)w2s, dinv,
                                                             hbuf, N, P16);
    gnn_aggregate_panel_k<<<aggBlocks, 256, 0, stream>>>(hbuf, rowptr, colidx,
                                                         dinv, b2, bufBh, bufBh, N, P16);
    // head
    gnn_final_k<<<(N + 63) / 64, 320, 0, stream>>>(bufBh, Wc, bc, out, N, (N + 1) * 2);
}

// Round 3
// 524.363 us; speedup vs baseline: 1.0698x; 1.0219x over previous
//
#include <hip/hip_runtime.h>
#include <stdint.h>

// GNN: 2-layer GCN + skip + classifier head. All fp32 in/out; edge_index int32.
// N=100000, E=1600000, F=H=128, OUT=40.
//
// Round-13: panel aggregation, latency-flattened.
// h' PANEL-MAJOR [8][N+1][16] bf16 (32 B/row/panel, 3.2 MB slab, row N = zeros).
// Panel p pinned to XCD p via blockIdx&7 (round-1 PROVED fetch 203->62 MB).
// Round-12 was latency-bound (VALU 34%, HBM 10%, nothing saturated): loop-carried
// colidx->gather chain x ~3.5 iterations/wave. This version: 4 nodes/wave,
// 16 lanes/node (8 slots x 2 hv), ONE unrolled 32-edge phase (4 independent colidx
// loads + 4 independent gathers per lane, zero-row clamp, no loop for deg<=32;
// P(deg>32) ~ 2e-4 -> rare 8-at-a-time tail). 3-hop reduce, early epilogue loads.

#define HID 128
#define OUTD 40
#define BSH 8                 // 256 nodes per bucket
#define BCAP 6144             // LDS colbuf entries per bucket (mean ~4350)
#define EPB 8192              // edges per scatter block
#define NBMAX 512

typedef __attribute__((ext_vector_type(8))) short short8;
typedef __attribute__((ext_vector_type(4))) float f32x4;
typedef __attribute__((ext_vector_type(2))) float f32x2;
typedef __attribute__((ext_vector_type(4))) unsigned int u32x4;

__device__ inline uint16_t f32_to_bf16(float f) {
    uint32_t u = __float_as_uint(f);
    uint32_t r = u + 0x7FFFu + ((u >> 16) & 1u);
    return (uint16_t)(r >> 16);
}
__device__ inline uint32_t pack_bf16x2(float lo, float hi) {
    return (uint32_t)f32_to_bf16(lo) | ((uint32_t)f32_to_bf16(hi) << 16);
}
__device__ inline float bf_lo(uint32_t u) { return __uint_as_float(u << 16); }
__device__ inline float bf_hi(uint32_t u) { return __uint_as_float(u & 0xFFFF0000u); }
// {even col, odd col} of one packed dword — f32x2 so the backend can use v_pk_add_f32
__device__ inline f32x2 up2(uint32_t u) {
    f32x2 r;
    r.x = __uint_as_float(u << 16);
    r.y = __uint_as_float(u & 0xFFFF0000u);
    return r;
}

// ---------------- CSR build ----------------

__global__ void gnn_count_k(const int* __restrict__ edges, int* __restrict__ cnt, int E) {
    int t = blockIdx.x * 256 + threadIdx.x;
    if (t < E) atomicAdd(&cnt[edges[E + t]], 1);
}

__global__ void gnn_scan_block_k(const int* __restrict__ cnt, int* __restrict__ scanbuf,
                                 int* __restrict__ bsum, int n) {
    __shared__ int s[256];
    int i = blockIdx.x * 256 + threadIdx.x;
    int v = (i < n) ? (cnt[i] + 1) : 0;
    s[threadIdx.x] = v;
    __syncthreads();
    for (int off = 1; off < 256; off <<= 1) {
        int t = 0;
        if (threadIdx.x >= off) t = s[threadIdx.x - off];
        __syncthreads();
        if (threadIdx.x >= off) s[threadIdx.x] += t;
        __syncthreads();
    }
    if (i < n) scanbuf[i] = s[threadIdx.x];
    if (threadIdx.x == 255) bsum[blockIdx.x] = s[255];
}

// blocks [0,nbk): rowptr + pcur + dinv (bsum prefix re-reduced per block).
// blocks [nbk, nbk+16): W swizzle fp32 -> bf16 B-fragment order.
// block nbk+16: zero-row init for hbuf (row n of each panel).
__global__ __launch_bounds__(256) void gnn_setup_k(const int* __restrict__ scanbuf,
                                                   const int* __restrict__ bsum,
                                                   const int* __restrict__ cnt,
                                                   int* __restrict__ rowptr,
                                                   int* __restrict__ pcur,
                                                   float* __restrict__ dinv,
                                                   const float* __restrict__ W1,
                                                   const float* __restrict__ W2,
                                                   uint16_t* __restrict__ w1s,
                                                   uint16_t* __restrict__ w2s,
                                                   uint16_t* __restrict__ hbuf,
                                                   int n, int nbk) {
    int b = blockIdx.x;
    if (b < nbk) {
        __shared__ int red[256];
        int t = threadIdx.x;
        int part = 0;
        for (int i = t; i < b; i += 256) part += bsum[i];
        red[t] = part;
        __syncthreads();
        for (int off = 128; off > 0; off >>= 1) {
            if (t < off) red[t] += red[t + off];
            __syncthreads();
        }
        int off0 = red[0];
        int i = b * 256 + t;
        if (i == 0) { rowptr[0] = 0; pcur[0] = 0; }
        if (i < n) {
            int v = scanbuf[i] + off0;
            rowptr[i + 1] = v;
            if (((i + 1) & 255) == 0) pcur[(i + 1) >> BSH] = v - (i + 1);
            dinv[i] = rsqrtf((float)(cnt[i] + 1));
        }
    } else if (b < nbk + 16) {
        int wb = b - nbk;                      // 0..15
        const float* W = (wb < 8) ? W1 : W2;
        uint16_t* O = (wb < 8) ? w1s : w2s;
        int t = (wb & 7) * 256 + threadIdx.x;  // 0..2047
        int lane = t & 63;
        int ksct = t >> 6;                     // ct*4+ks
        int nn = (ksct >> 2) * 16 + (lane & 15);
        int k0 = (ksct & 3) * 32 + (lane >> 4) * 8;
        uint32_t d[4];
#pragma unroll
        for (int j = 0; j < 4; ++j)
            d[j] = pack_bf16x2(W[(size_t)(k0 + 2 * j) * HID + nn],
                               W[(size_t)(k0 + 2 * j + 1) * HID + nn]);
        *(uint4*)(O + (size_t)t * 8) = make_uint4(d[0], d[1], d[2], d[3]);
    } else {
        // zero rows: hbuf[panel][n][0..15] = 0 for all 8 panels
        if (threadIdx.x < 128) {
            int panel = threadIdx.x >> 4;
            int col = threadIdx.x & 15;
            size_t p16 = (size_t)(n + 1) * 16;
            hbuf[(size_t)panel * p16 + (size_t)n * 16 + col] = 0;
        }
    }
}

__global__ __launch_bounds__(256) void gnn_bucket_scatter_k(const int* __restrict__ edges,
                                                            int* __restrict__ pcur,
                                                            uint32_t* __restrict__ pairbuf,
                                                            int E, int NB) {
    __shared__ int hist[NBMAX];
    int e0 = blockIdx.x * EPB;
    int e1 = min(E, e0 + EPB);
    for (int b = threadIdx.x; b < NB; b += 256) hist[b] = 0;
    __syncthreads();
    for (int e = e0 + threadIdx.x; e < e1; e += 256)
        atomicAdd(&hist[edges[E + e] >> BSH], 1);
    __syncthreads();
    for (int b = threadIdx.x; b < NB; b += 256) {
        int c = hist[b];
        hist[b] = (c > 0) ? atomicAdd(&pcur[b], c) : 0;
    }
    __syncthreads();
    for (int e = e0 + threadIdx.x; e < e1; e += 256) {
        int src = edges[e];
        int dst = edges[E + e];
        int pos = atomicAdd(&hist[dst >> BSH], 1);
        pairbuf[pos] = ((uint32_t)(dst & 255) << 24) | (uint32_t)src;
    }
}

__global__ __launch_bounds__(256) void gnn_build_csr_k(const uint32_t* __restrict__ pairbuf,
                                                       const int* __restrict__ rowptr,
                                                       int* __restrict__ colidx,
                                                       int* __restrict__ gcur, int n) {
    __shared__ int cur[256];
    __shared__ int colbuf[BCAP];
    int b = blockIdx.x;
    int nb0 = b << BSH;
    int nb1 = min(n, nb0 + 256);
    int nn = nb1 - nb0;
    int segbeg = rowptr[nb0];
    int segend = rowptr[nb1];
    int seglen = segend - segbeg;
    int pairbeg = segbeg - nb0;
    int npairs = (segend - nb1) - pairbeg;

    if (seglen <= BCAP) {
        if (threadIdx.x < nn) {
            int node = nb0 + threadIdx.x;
            int rel = rowptr[node] - segbeg;
            colbuf[rel] = node;            // self loop
            cur[threadIdx.x] = rel + 1;
        }
        __syncthreads();
        for (int p = threadIdx.x; p < npairs; p += 256) {
            uint32_t pr = pairbuf[pairbeg + p];
            int pos = atomicAdd(&cur[pr >> 24], 1);
            colbuf[pos] = (int)(pr & 0xFFFFFFu);
        }
        __syncthreads();
        for (int i = threadIdx.x; i < seglen; i += 256)
            colidx[segbeg + i] = colbuf[i];
    } else {
        if (threadIdx.x < nn) {
            int node = nb0 + threadIdx.x;
            colidx[rowptr[node]] = node;
        }
        __syncthreads();
        for (int p = threadIdx.x; p < npairs; p += 256) {
            uint32_t pr = pairbuf[pairbeg + p];
            int dst = nb0 + (int)(pr >> 24);
            int pos = atomicAdd(&gcur[dst], 1);
            colidx[rowptr[dst] + 1 + pos] = (int)(pr & 0xFFFFFFu);
        }
    }
}

// ---------------- MFMA GEMM [n,128] @ [128,128], row-scaled by dinv -> bf16 h' ----------------
// 256 threads = 4 waves x 16 rows. Per wave: 8 col-tiles x 4 K-steps of 16x16x32 bf16.
// Output PANEL-MAJOR: outh[(col>>4)*p16 + row*16 + (col&15)], p16 = (n+1)*16.
// ABF16 path reads panel-major bf16 A (aggregate output layout, same stride).

template <bool ABF16>
__global__ __launch_bounds__(256) void gnn_gemm_mfma_k(const void* __restrict__ Aptr,
                                                       const uint32_t* __restrict__ Wsw,
                                                       const float* __restrict__ dinv,
                                                       uint16_t* __restrict__ outh,
                                                       int n, int p16) {
    int wave = threadIdx.x >> 6;
    int lane = threadIdx.x & 63;
    int m = lane & 15;
    int q = lane >> 4;
    int row0 = blockIdx.x * 64 + wave * 16;
    int arow = min(row0 + m, n - 1);
    const size_t P16 = (size_t)p16;

    f32x4 acc[8];
#pragma unroll
    for (int i = 0; i < 8; ++i) acc[i] = (f32x4){0.f, 0.f, 0.f, 0.f};

#pragma unroll
    for (int ks = 0; ks < 4; ++ks) {
        short8 a;
        if (ABF16) {
            // cols k0 = ks*32 + q*8 -> panel 2*ks + (q>>1), in-panel offset (q&1)*8
            const uint16_t* Ab = (const uint16_t*)Aptr;
            uint4 u = *(const uint4*)(Ab + (size_t)(2 * ks + (q >> 1)) * P16 +
                                      (size_t)arow * 16 + (q & 1) * 8);
            a = __builtin_bit_cast(short8, u);
        } else {
            const float* Af = (const float*)Aptr + (size_t)arow * HID + ks * 32 + q * 8;
            uint4 u0 = *(const uint4*)(Af);
            uint4 u1 = *(const uint4*)(Af + 4);
            uint4 p;
            p.x = pack_bf16x2(__uint_as_float(u0.x), __uint_as_float(u0.y));
            p.y = pack_bf16x2(__uint_as_float(u0.z), __uint_as_float(u0.w));
            p.z = pack_bf16x2(__uint_as_float(u1.x), __uint_as_float(u1.y));
            p.w = pack_bf16x2(__uint_as_float(u1.z), __uint_as_float(u1.w));
            a = __builtin_bit_cast(short8, p);
        }
#pragma unroll
        for (int ct = 0; ct < 8; ++ct) {
            uint4 bu = *(const uint4*)(Wsw + ((size_t)(ct * 4 + ks) * 64 + lane) * 4);
            short8 bfr = __builtin_bit_cast(short8, bu);
            acc[ct] = __builtin_amdgcn_mfma_f32_16x16x32_bf16(a, bfr, acc[ct], 0, 0, 0);
        }
    }

    float dv[4];
#pragma unroll
    for (int r = 0; r < 4; ++r) dv[r] = dinv[min(row0 + q * 4 + r, n - 1)];

#pragma unroll
    for (int ct = 0; ct < 8; ++ct) {
#pragma unroll
        for (int r = 0; r < 4; ++r) {
            int rr = row0 + q * 4 + r;
            if (rr < n)
                outh[(size_t)ct * P16 + (size_t)rr * 16 + m] = f32_to_bf16(acc[ct][r] * dv[r]);
        }
    }
}

// ---------------- aggregation: panel-partitioned, XCD-pinned, latency-flat ----------------
// grid = 8 * ceil(N/16); panel = blockIdx&7 (-> XCD p), chunk = blockIdx>>3.
// Block = 4 waves; wave = 4 nodes x (8 slots x 2 hv). Single unrolled 32-edge phase:
// 4 independent clamped colidx loads + 4 independent gathers per lane (no loop-carried
// dep); slots past the degree clamp j -> n (zero row, L1-resident). deg>32 tail is a
// rare 8-at-a-time loop. 3-hop shfl reduce; epilogue loads issued before the reduce.

__global__ __launch_bounds__(256) void gnn_aggregate_panel_k(
    const uint16_t* __restrict__ hp,      // [8][n+1][16] bf16 panel-major; row n = zeros
    const int* __restrict__ rowptr, const int* __restrict__ colidx,
    const float* __restrict__ dinv, const float* __restrict__ bias,
    const uint16_t* __restrict__ skipb,   // panel-major (same stride) or null
    uint16_t* __restrict__ outp, int n, int p16, int etot) {
    const int panel = blockIdx.x & 7;
    const int lane = threadIdx.x & 63;
    const int wave = threadIdx.x >> 6;
    const int grp = lane >> 4;            // node within wave (0..3)
    const int sub = lane & 15;
    const int slot = sub >> 1;            // 0..7
    const int hv = sub & 1;               // 16B half of the 32B row
    int node = (blockIdx.x >> 3) * 16 + wave * 4 + grp;
    const bool nodeOK = node < n;
    if (!nodeOK) node = n - 1;

    const char* __restrict__ hpB = (const char*)(hp + (size_t)panel * p16);
    const uint32_t hvo = (uint32_t)hv << 4;

    const int beg = rowptr[node];
    const int end = rowptr[node + 1];
    const int es = beg + slot;
    const int emax = etot - 1;

    // 4 independent clamped colidx loads (cover edges beg .. beg+31)
    int c0 = __builtin_nontemporal_load(colidx + min(es, emax));
    int c1 = __builtin_nontemporal_load(colidx + min(es + 8, emax));
    int c2 = __builtin_nontemporal_load(colidx + min(es + 16, emax));
    int c3 = __builtin_nontemporal_load(colidx + min(es + 24, emax));
    const int j0 = (es < end) ? c0 : n;
    const int j1 = (es + 8 < end) ? c1 : n;
    const int j2 = (es + 16 < end) ? c2 : n;
    const int j3 = (es + 24 < end) ? c3 : n;

    // 4 independent gathers
    const uint4 u0 = *(const uint4*)(hpB + (((uint32_t)j0 << 5) | hvo));
    const uint4 u1 = *(const uint4*)(hpB + (((uint32_t)j1 << 5) | hvo));
    const uint4 u2 = *(const uint4*)(hpB + (((uint32_t)j2 << 5) | hvo));
    const uint4 u3 = *(const uint4*)(hpB + (((uint32_t)j3 << 5) | hvo));

    f32x2 acc[4];
    acc[0] = up2(u0.x); acc[1] = up2(u0.y); acc[2] = up2(u0.z); acc[3] = up2(u0.w);
    acc[0] += up2(u1.x); acc[1] += up2(u1.y); acc[2] += up2(u1.z); acc[3] += up2(u1.w);
    acc[0] += up2(u2.x); acc[1] += up2(u2.y); acc[2] += up2(u2.z); acc[3] += up2(u2.w);
    acc[0] += up2(u3.x); acc[1] += up2(u3.y); acc[2] += up2(u3.z); acc[3] += up2(u3.w);

    // rare tail: deg > 32 (P ~ 2e-4 at Poisson(16)+1)
    for (int e0 = beg + 32; e0 < end; e0 += 8) {
        int e = e0 + slot;
        int c = __builtin_nontemporal_load(colidx + min(e, emax));
        int j = (e < end) ? c : n;
        uint4 u = *(const uint4*)(hpB + (((uint32_t)j << 5) | hvo));
        acc[0] += up2(u.x); acc[1] += up2(u.y); acc[2] += up2(u.z); acc[3] += up2(u.w);
    }

    // epilogue loads issued before the reduce (hide latency under shfl chain)
    const size_t off16 = (size_t)panel * p16 + (size_t)node * 16 + hv * 8;
    float di = 0.f;
    float4 b0 = make_float4(0.f, 0.f, 0.f, 0.f), b1 = b0;
    u32x4 sv = (u32x4){0u, 0u, 0u, 0u};
    if (sub < 2) {
        di = dinv[node];
        const float* bp = bias + panel * 16 + hv * 8;
        b0 = *(const float4*)bp;
        b1 = *(const float4*)(bp + 4);
        if (skipb) sv = __builtin_nontemporal_load((const u32x4*)(skipb + off16));
    }

    float a8[8];
#pragma unroll
    for (int i = 0; i < 4; ++i) { a8[2 * i] = acc[i].x; a8[2 * i + 1] = acc[i].y; }
    // reduce over slot (lane bits 1..3); partners always share node and hv
#pragma unroll
    for (int k = 0; k < 8; ++k) {
        a8[k] += __shfl_xor(a8[k], 2, 64);
        a8[k] += __shfl_xor(a8[k], 4, 64);
        a8[k] += __shfl_xor(a8[k], 8, 64);
    }

    if (sub < 2 && nodeOK) {
        float o[8];
        o[0] = fmaxf(di * a8[0] + b0.x, 0.f);
        o[1] = fmaxf(di * a8[1] + b0.y, 0.f);
        o[2] = fmaxf(di * a8[2] + b0.z, 0.f);
        o[3] = fmaxf(di * a8[3] + b0.w, 0.f);
        o[4] = fmaxf(di * a8[4] + b1.x, 0.f);
        o[5] = fmaxf(di * a8[5] + b1.y, 0.f);
        o[6] = fmaxf(di * a8[6] + b1.z, 0.f);
        o[7] = fmaxf(di * a8[7] + b1.w, 0.f);
        if (skipb) {
            o[0] += bf_lo(sv[0]); o[1] += bf_hi(sv[0]);
            o[2] += bf_lo(sv[1]); o[3] += bf_hi(sv[1]);
            o[4] += bf_lo(sv[2]); o[5] += bf_hi(sv[2]);
            o[6] += bf_lo(sv[3]); o[7] += bf_hi(sv[3]);
        }
        u32x4 pv;
        pv[0] = pack_bf16x2(o[0], o[1]);
        pv[1] = pack_bf16x2(o[2], o[3]);
        pv[2] = pack_bf16x2(o[4], o[5]);
        pv[3] = pack_bf16x2(o[6], o[7]);
        __builtin_nontemporal_store(pv, (u32x4*)(outp + off16));
    }
}

// ---------------- final: bf16 sum[8][n+1][16] (panel-major) @ Wc[128,40] + bc -> fp32 ----------------

__global__ __launch_bounds__(320) void gnn_final_k(const uint16_t* __restrict__ sumh,
                                                   const float* __restrict__ wc,
                                                   const float* __restrict__ bc,
                                                   float* __restrict__ out, int n, int ps4) {
    __shared__ float a[64 * HID];  // 32 KB, float4 block (r, c4) at r*32 + (c4 ^ (r&7))
    const int tx = threadIdx.x % 10;
    const int ty = threadIdx.x / 10;
    const int row0 = blockIdx.x * 64;

    {
        const uint4* S8 = (const uint4*)sumh;  // panel-major: [8][(n+1)][2] uint4
        const size_t pstride = (size_t)ps4;
        float4* s4 = (float4*)a;
        for (int idx = threadIdx.x; idx < 64 * 16; idx += 320) {
            int r = idx >> 4, c8 = idx & 15;
            uint4 v = make_uint4(0u, 0u, 0u, 0u);
            if (row0 + r < n)
                v = S8[(size_t)(c8 >> 1) * pstride + (size_t)(row0 + r) * 2 + (c8 & 1)];
            float4 f0 = make_float4(bf_lo(v.x), bf_hi(v.x), bf_lo(v.y), bf_hi(v.y));
            float4 f1 = make_float4(bf_lo(v.z), bf_hi(v.z), bf_lo(v.w), bf_hi(v.w));
            s4[r * 32 + ((2 * c8) ^ (r & 7))] = f0;
            s4[r * 32 + ((2 * c8 + 1) ^ (r & 7))] = f1;
        }
    }
    __syncthreads();

    float acc[2][4];
    {
        float b0 = bc[tx * 4], b1 = bc[tx * 4 + 1], b2 = bc[tx * 4 + 2], b3 = bc[tx * 4 + 3];
        acc[0][0] = b0; acc[0][1] = b1; acc[0][2] = b2; acc[0][3] = b3;
        acc[1][0] = b0; acc[1][1] = b1; acc[1][2] = b2; acc[1][3] = b3;
    }
    const float* wp = wc + tx * 4;
    const float4* s4 = (const float4*)a;

#pragma unroll 2
    for (int k = 0; k < HID; k += 4) {
        int c4 = k >> 2;
        float ar[2][4];
#pragma unroll
        for (int r = 0; r < 2; ++r) {
            int row = ty * 2 + r;
            *(float4*)&ar[r][0] = s4[row * 32 + (c4 ^ (row & 7))];
        }
#pragma unroll
        for (int kk = 0; kk < 4; ++kk) {
            float4 w = *(const float4*)(wp + (size_t)(k + kk) * OUTD);
#pragma unroll
            for (int r = 0; r < 2; ++r) {
                acc[r][0] += ar[r][kk] * w.x;
                acc[r][1] += ar[r][kk] * w.y;
                acc[r][2] += ar[r][kk] * w.z;
                acc[r][3] += ar[r][kk] * w.w;
            }
        }
    }

#pragma unroll
    for (int r = 0; r < 2; ++r) {
        int row = row0 + ty * 2 + r;
        if (row < n) {
            float4 v = make_float4(acc[r][0], acc[r][1], acc[r][2], acc[r][3]);
            *(float4*)(out + (size_t)row * OUTD + tx * 4) = v;
        }
    }
}

// ---------------- launch ----------------

extern "C" void kernel_launch(void* const* d_in, const int* in_sizes, int n_in,
                              void* d_out, int out_size, void* d_ws, size_t ws_size,
                              hipStream_t stream) {
    const int N = in_sizes[0] / HID;   // 100000
    const int E = in_sizes[7] / 2;     // 1600000

    const float* x  = (const float*)d_in[0];
    const float* W1 = (const float*)d_in[1];
    const float* b1 = (const float*)d_in[2];
    const float* W2 = (const float*)d_in[3];
    const float* b2 = (const float*)d_in[4];
    const float* Wc = (const float*)d_in[5];
    const float* bc = (const float*)d_in[6];
    const int* edges = (const int*)d_in[7];
    float* out = (float*)d_out;

    const int P16 = (N + 1) * 16;      // panel stride, uint16 units
    const int ETOT = E + N;            // total CSR entries (edges + self loops)

    // workspace carve-up (256B aligned), ~66 MB total
    char* w = (char*)d_ws;
    auto alloc = [&](size_t bytes) -> char* {
        char* p = w;
        w += (bytes + 255) & ~(size_t)255;
        return p;
    };
    uint16_t* hbuf  = (uint16_t*)alloc((size_t)(N + 1) * HID * 2);  // h' bf16 panel-major + zero row
    uint16_t* bufBh = (uint16_t*)alloc((size_t)(N + 1) * HID * 2);  // bf16 out1, then bf16 sum
    int*   cnt     = (int*)alloc((size_t)N * 4);
    int*   gcur    = (int*)alloc((size_t)N * 4);
    int*   rowptr  = (int*)alloc((size_t)(N + 1) * 4);
    int*   scanbuf = (int*)alloc((size_t)N * 4);
    int*   bsum    = (int*)alloc(512 * 4);
    int*   pcur    = (int*)alloc(512 * 4);
    int*   colidx  = (int*)alloc((size_t)(E + N) * 4);
    float* dinv    = (float*)alloc((size_t)N * 4);
    uint32_t* pairbuf = (uint32_t*)alloc((size_t)E * 4);
    uint16_t* w1s  = (uint16_t*)alloc(HID * HID * 2);
    uint16_t* w2s  = (uint16_t*)alloc(HID * HID * 2);

    const int nb1 = (N + 255) / 256;   // scan blocks (391)
    const int NB  = (N + 255) >> BSH;  // buckets (391)

    size_t cntspan = (size_t)((char*)rowptr - (char*)cnt);
    hipMemsetAsync(cnt, 0, cntspan, stream);

    gnn_count_k<<<(E + 255) / 256, 256, 0, stream>>>(edges, cnt, E);
    gnn_scan_block_k<<<nb1, 256, 0, stream>>>(cnt, scanbuf, bsum, N);
    gnn_setup_k<<<nb1 + 17, 256, 0, stream>>>(scanbuf, bsum, cnt, rowptr, pcur, dinv,
                                              W1, W2, w1s, w2s, hbuf, N, nb1);
    gnn_bucket_scatter_k<<<(E + EPB - 1) / EPB, 256, 0, stream>>>(edges, pcur, pairbuf, E, NB);
    gnn_build_csr_k<<<NB, 256, 0, stream>>>(pairbuf, rowptr, colidx, gcur, N);

    const int aggBlocks = ((N + 15) / 16) * 8;   // 8 panels, XCD-pinned via blockIdx&7

    // layer 1: h1' = bf16(dinv * (x @ W1)) ; bufBh = bf16(relu(dinv*agg(h1') + b1))
    gnn_gemm_mfma_k<false><<<(N + 63) / 64, 256, 0, stream>>>(x, (const uint32_t*)w1s, dinv,
                                                              hbuf, N, P16);
    gnn_aggregate_panel_k<<<aggBlocks, 256, 0, stream>>>(hbuf, rowptr, colidx,
                                                         dinv, b1, nullptr, bufBh, N, P16, ETOT);
    // layer 2: h2' = bf16(dinv * (out1 @ W2)) ; bufBh = bf16(relu(...) + out1) in place
    gnn_gemm_mfma_k<true><<<(N + 63) / 64, 256, 0, stream>>>(bufBh, (const uint32_t*)w2s, dinv,
                                                             hbuf, N, P16);
    gnn_aggregate_panel_k<<<aggBlocks, 256, 0, stream>>>(hbuf, rowptr, colidx,
                                                         dinv, b2, bufBh, bufBh, N, P16, ETOT);
    // head
    gnn_final_k<<<(N + 63) / 64, 320, 0, stream>>>(bufBh, Wc, bc, out, N, (N + 1) * 2);
}

// Round 4
// 367.787 us; speedup vs baseline: 1.5253x; 1.4257x over previous
//
#include <hip/hip_runtime.h>
#include <stdint.h>

// GNN: 2-layer GCN + skip + classifier head. All fp32 in/out; edge_index int32.
// N=100000, E=1600000, F=H=128, OUT=40.
//
// Round-14: revert to round-9 row-major aggregation (68us, proven optimal under the
// L2-line-request model: 4 line-req/edge is the bf16 minimum; panel variants doubled
// requests via half-line rows -> 123-140us, all reverted). New: fused CSR build —
// count_k (1.6M random global atomics) + scan_block + setup-prefix replaced by
// bucket-histogram + 1-block bucket scan + per-bucket LDS degree scan inside build.

#define HID 128
#define OUTD 40
#define BSH 8                 // 256 nodes per bucket
#define BCAP 6144             // LDS colbuf entries per bucket (mean ~4350)
#define EPB 8192              // edges per hist/scatter block
#define NBMAX 512

typedef __attribute__((ext_vector_type(8))) short short8;
typedef __attribute__((ext_vector_type(4))) float f32x4;
typedef __attribute__((ext_vector_type(2))) float f32x2;

__device__ inline uint16_t f32_to_bf16(float f) {
    uint32_t u = __float_as_uint(f);
    uint32_t r = u + 0x7FFFu + ((u >> 16) & 1u);
    return (uint16_t)(r >> 16);
}
__device__ inline uint32_t pack_bf16x2(float lo, float hi) {
    return (uint32_t)f32_to_bf16(lo) | ((uint32_t)f32_to_bf16(hi) << 16);
}
__device__ inline float bf_lo(uint32_t u) { return __uint_as_float(u << 16); }
__device__ inline float bf_hi(uint32_t u) { return __uint_as_float(u & 0xFFFF0000u); }
// {even col, odd col} of one packed dword — f32x2 so the backend can use v_pk_add_f32
__device__ inline f32x2 up2(uint32_t u) {
    f32x2 r;
    r.x = __uint_as_float(u << 16);
    r.y = __uint_as_float(u & 0xFFFF0000u);
    return r;
}

// ---------------- CSR build (fused) ----------------

// per-chunk LDS histogram of dst buckets -> global bucket counts
__global__ __launch_bounds__(256) void gnn_hist_k(const int* __restrict__ edges,
                                                  int* __restrict__ bcnt, int E, int NB) {
    __shared__ int h[NBMAX];
    int e0 = blockIdx.x * EPB;
    int e1 = min(E, e0 + EPB);
    for (int b = threadIdx.x; b < NB; b += 256) h[b] = 0;
    __syncthreads();
    for (int e = e0 + threadIdx.x; e < e1; e += 256)
        atomicAdd(&h[edges[E + e] >> BSH], 1);
    __syncthreads();
    for (int b = threadIdx.x; b < NB; b += 256) {
        int c = h[b];
        if (c > 0) atomicAdd(&bcnt[b], c);
    }
}

// block 0: exclusive scan of (bcnt[b] + nodes_b) over buckets -> bucketoff (NB+1), pcur.
// blocks 1..16: W swizzle fp32 -> bf16 B-fragment order.
// Wsw[((ct*4+ks)*64+lane)*8+j] = bf16(W[(ks*32+(lane>>4)*8+j)*128 + ct*16+(lane&15)])
__global__ __launch_bounds__(512) void gnn_bucketscan_k(const int* __restrict__ bcnt,
                                                        int* __restrict__ bucketoff,
                                                        int* __restrict__ pcur,
                                                        const float* __restrict__ W1,
                                                        const float* __restrict__ W2,
                                                        uint16_t* __restrict__ w1s,
                                                        uint16_t* __restrict__ w2s,
                                                        int n, int NB) {
    if (blockIdx.x == 0) {
        __shared__ int s[512];
        int t = threadIdx.x;
        int v = 0;
        if (t < NB) v = bcnt[t] + min(256, n - (t << BSH));
        s[t] = v;
        __syncthreads();
        for (int off = 1; off < 512; off <<= 1) {
            int x = 0;
            if (t >= off) x = s[t - off];
            __syncthreads();
            if (t >= off) s[t] += x;
            __syncthreads();
        }
        int excl = s[t] - v;
        if (t <= NB) {
            bucketoff[t] = excl;
            if (t < NB) pcur[t] = excl - (t << BSH);
        }
    } else if (threadIdx.x < 256) {
        int wb = blockIdx.x - 1;               // 0..15
        const float* W = (wb < 8) ? W1 : W2;
        uint16_t* O = (wb < 8) ? w1s : w2s;
        int t = (wb & 7) * 256 + threadIdx.x;  // 0..2047
        int lane = t & 63;
        int ksct = t >> 6;                     // ct*4+ks
        int nn = (ksct >> 2) * 16 + (lane & 15);
        int k0 = (ksct & 3) * 32 + (lane >> 4) * 8;
        uint32_t d[4];
#pragma unroll
        for (int j = 0; j < 4; ++j)
            d[j] = pack_bf16x2(W[(size_t)(k0 + 2 * j) * HID + nn],
                               W[(size_t)(k0 + 2 * j + 1) * HID + nn]);
        *(uint4*)(O + (size_t)t * 8) = make_uint4(d[0], d[1], d[2], d[3]);
    }
}

__global__ __launch_bounds__(256) void gnn_bucket_scatter_k(const int* __restrict__ edges,
                                                            int* __restrict__ pcur,
                                                            uint32_t* __restrict__ pairbuf,
                                                            int E, int NB) {
    __shared__ int hist[NBMAX];
    int e0 = blockIdx.x * EPB;
    int e1 = min(E, e0 + EPB);
    for (int b = threadIdx.x; b < NB; b += 256) hist[b] = 0;
    __syncthreads();
    for (int e = e0 + threadIdx.x; e < e1; e += 256)
        atomicAdd(&hist[edges[E + e] >> BSH], 1);
    __syncthreads();
    for (int b = threadIdx.x; b < NB; b += 256) {
        int c = hist[b];
        hist[b] = (c > 0) ? atomicAdd(&pcur[b], c) : 0;
    }
    __syncthreads();
    for (int e = e0 + threadIdx.x; e < e1; e += 256) {
        int src = edges[e];
        int dst = edges[E + e];
        int pos = atomicAdd(&hist[dst >> BSH], 1);
        pairbuf[pos] = ((uint32_t)(dst & 255) << 24) | (uint32_t)src;
    }
}

// per bucket: LDS degree histogram over pairs -> 256-scan -> rowptr/dinv,
// self-loop + pair placement into colbuf (or directly to colidx on overflow).
__global__ __launch_bounds__(256) void gnn_build_csr_k(const uint32_t* __restrict__ pairbuf,
                                                       const int* __restrict__ bucketoff,
                                                       int* __restrict__ rowptr,
                                                       float* __restrict__ dinv,
                                                       int* __restrict__ colidx, int n) {
    __shared__ int deg[256];     // histogram, then reused as per-node cursor
    __shared__ int scn[256];
    __shared__ int colbuf[BCAP];
    int b = blockIdx.x;
    int nb0 = b << BSH;
    int nb1 = min(n, nb0 + 256);
    int nn = nb1 - nb0;
    int segbeg = bucketoff[b];
    int segend = bucketoff[b + 1];
    int seglen = segend - segbeg;
    int pairbeg = segbeg - nb0;
    int npairs = seglen - nn;
    int t = threadIdx.x;

    deg[t] = 0;
    __syncthreads();
    for (int p = t; p < npairs; p += 256)
        atomicAdd(&deg[pairbuf[pairbeg + p] >> 24], 1);
    __syncthreads();

    int d = (t < nn) ? deg[t] : 0;
    int v = (t < nn) ? d + 1 : 0;
    scn[t] = v;
    __syncthreads();
    for (int off = 1; off < 256; off <<= 1) {
        int x = 0;
        if (t >= off) x = scn[t - off];
        __syncthreads();
        if (t >= off) scn[t] += x;
        __syncthreads();
    }
    int rel = scn[t] - v;                 // exclusive prefix
    if (t < nn) {
        rowptr[nb0 + t + 1] = segbeg + scn[t];
        dinv[nb0 + t] = rsqrtf((float)(d + 1));
    }
    if (t == 0) rowptr[nb0] = segbeg;
    __syncthreads();

    if (seglen <= BCAP) {
        if (t < nn) {
            colbuf[rel] = nb0 + t;        // self loop
            deg[t] = rel + 1;
        }
        __syncthreads();
        for (int p = t; p < npairs; p += 256) {
            uint32_t pr = pairbuf[pairbeg + p];
            int pos = atomicAdd(&deg[pr >> 24], 1);
            colbuf[pos] = (int)(pr & 0xFFFFFFu);
        }
        __syncthreads();
        for (int i = t; i < seglen; i += 256)
            colidx[segbeg + i] = colbuf[i];
    } else {
        if (t < nn) {
            colidx[segbeg + rel] = nb0 + t;
            deg[t] = rel + 1;
        }
        __syncthreads();
        for (int p = t; p < npairs; p += 256) {
            uint32_t pr = pairbuf[pairbeg + p];
            int pos = atomicAdd(&deg[pr >> 24], 1);
            colidx[segbeg + pos] = (int)(pr & 0xFFFFFFu);
        }
    }
}

// ---------------- MFMA GEMM [n,128] @ [128,128], row-scaled by dinv -> bf16 h' ----------------
// 256 threads = 4 waves x 16 rows. Per wave: 8 col-tiles x 4 K-steps of 16x16x32 bf16.
// A-frag straight from global; ABF16 picks fp32/bf16 A. D: col=lane&15, row=quad*4+reg.

template <bool ABF16>
__global__ __launch_bounds__(256) void gnn_gemm_mfma_k(const void* __restrict__ Aptr,
                                                       const uint32_t* __restrict__ Wsw,
                                                       const float* __restrict__ dinv,
                                                       uint16_t* __restrict__ outh, int n) {
    int wave = threadIdx.x >> 6;
    int lane = threadIdx.x & 63;
    int m = lane & 15;
    int q = lane >> 4;
    int row0 = blockIdx.x * 64 + wave * 16;
    int arow = min(row0 + m, n - 1);

    f32x4 acc[8];
#pragma unroll
    for (int i = 0; i < 8; ++i) acc[i] = (f32x4){0.f, 0.f, 0.f, 0.f};

#pragma unroll
    for (int ks = 0; ks < 4; ++ks) {
        short8 a;
        if (ABF16) {
            const uint16_t* Ab = (const uint16_t*)Aptr;
            uint4 u = *(const uint4*)(Ab + (size_t)arow * HID + ks * 32 + q * 8);
            a = __builtin_bit_cast(short8, u);
        } else {
            const float* Af = (const float*)Aptr + (size_t)arow * HID + ks * 32 + q * 8;
            uint4 u0 = *(const uint4*)(Af);
            uint4 u1 = *(const uint4*)(Af + 4);
            uint4 p;
            p.x = pack_bf16x2(__uint_as_float(u0.x), __uint_as_float(u0.y));
            p.y = pack_bf16x2(__uint_as_float(u0.z), __uint_as_float(u0.w));
            p.z = pack_bf16x2(__uint_as_float(u1.x), __uint_as_float(u1.y));
            p.w = pack_bf16x2(__uint_as_float(u1.z), __uint_as_float(u1.w));
            a = __builtin_bit_cast(short8, p);
        }
#pragma unroll
        for (int ct = 0; ct < 8; ++ct) {
            uint4 bu = *(const uint4*)(Wsw + ((size_t)(ct * 4 + ks) * 64 + lane) * 4);
            short8 bfr = __builtin_bit_cast(short8, bu);
            acc[ct] = __builtin_amdgcn_mfma_f32_16x16x32_bf16(a, bfr, acc[ct], 0, 0, 0);
        }
    }

    float dv[4];
#pragma unroll
    for (int r = 0; r < 4; ++r) dv[r] = dinv[min(row0 + q * 4 + r, n - 1)];

#pragma unroll
    for (int ct = 0; ct < 8; ++ct) {
#pragma unroll
        for (int r = 0; r < 4; ++r) {
            int rr = row0 + q * 4 + r;
            if (rr < n)
                outh[(size_t)rr * HID + ct * 16 + m] = f32_to_bf16(acc[ct][r] * dv[r]);
        }
    }
}

// ---------------- aggregation: one wave per node, grouped dwordx4 gather ----------------
// 64 lanes = 4 edge-groups x 16 lanes; f32x2 packed accumulate (v_pk_add_f32);
// xor-butterfly reduce; lanes 0..31 bf16 epilogue (in-place skip safe).

__global__ __launch_bounds__(256) void gnn_aggregate_k(const uint4* __restrict__ h4,
                                const int* __restrict__ rowptr,
                                const int* __restrict__ colidx, const float* __restrict__ dinv,
                                const float* __restrict__ bias,
                                const uint16_t* __restrict__ skipb,
                                uint16_t* __restrict__ outsh, int n) {
    int node = blockIdx.x * 4 + (threadIdx.x >> 6);
    if (node >= n) return;
    int lane = threadIdx.x & 63;
    int g = lane >> 4;
    int sub = lane & 15;
    int beg = rowptr[node];
    int end = rowptr[node + 1];
    f32x2 acc2[4];
#pragma unroll
    for (int i = 0; i < 4; ++i) acc2[i] = (f32x2){0.f, 0.f};
    int e = beg;
    for (; e + 15 < end; e += 16) {
        int j0 = colidx[e + g];
        int j1 = colidx[e + 4 + g];
        int j2 = colidx[e + 8 + g];
        int j3 = colidx[e + 12 + g];
        uint4 u0 = h4[(size_t)j0 * 16 + sub];
        uint4 u1 = h4[(size_t)j1 * 16 + sub];
        uint4 u2 = h4[(size_t)j2 * 16 + sub];
        uint4 u3 = h4[(size_t)j3 * 16 + sub];
        acc2[0] += up2(u0.x); acc2[1] += up2(u0.y); acc2[2] += up2(u0.z); acc2[3] += up2(u0.w);
        acc2[0] += up2(u1.x); acc2[1] += up2(u1.y); acc2[2] += up2(u1.z); acc2[3] += up2(u1.w);
        acc2[0] += up2(u2.x); acc2[1] += up2(u2.y); acc2[2] += up2(u2.z); acc2[3] += up2(u2.w);
        acc2[0] += up2(u3.x); acc2[1] += up2(u3.y); acc2[2] += up2(u3.z); acc2[3] += up2(u3.w);
    }
    for (; e + 3 < end; e += 4) {
        int j = colidx[e + g];
        uint4 u = h4[(size_t)j * 16 + sub];
        acc2[0] += up2(u.x); acc2[1] += up2(u.y); acc2[2] += up2(u.z); acc2[3] += up2(u.w);
    }
    if (g < end - e) {
        int j = colidx[e + g];
        uint4 u = h4[(size_t)j * 16 + sub];
        acc2[0] += up2(u.x); acc2[1] += up2(u.y); acc2[2] += up2(u.z); acc2[3] += up2(u.w);
    }
    float a8[8];
#pragma unroll
    for (int i = 0; i < 4; ++i) { a8[2 * i] = acc2[i].x; a8[2 * i + 1] = acc2[i].y; }
#pragma unroll
    for (int k = 0; k < 8; ++k) {
        a8[k] += __shfl_xor(a8[k], 16, 64);
        a8[k] += __shfl_xor(a8[k], 32, 64);
    }
    if (lane < 32) {
        int half = lane >> 4;
        int col = sub * 8 + half * 4;
        float di = dinv[node];
        float4 bv = *(const float4*)(bias + col);
        float o0 = fmaxf(di * a8[half * 4 + 0] + bv.x, 0.0f);
        float o1 = fmaxf(di * a8[half * 4 + 1] + bv.y, 0.0f);
        float o2 = fmaxf(di * a8[half * 4 + 2] + bv.z, 0.0f);
        float o3 = fmaxf(di * a8[half * 4 + 3] + bv.w, 0.0f);
        if (skipb) {
            uint2 sv = *(const uint2*)(skipb + (size_t)node * HID + col);
            o0 += bf_lo(sv.x); o1 += bf_hi(sv.x);
            o2 += bf_lo(sv.y); o3 += bf_hi(sv.y);
        }
        uint2 sh;
        sh.x = pack_bf16x2(o0, o1);
        sh.y = pack_bf16x2(o2, o3);
        *(uint2*)(outsh + (size_t)node * HID + col) = sh;
    }
}

// ---------------- final: bf16 sum[n,128] @ Wc[128,40] + bc -> fp32 ----------------

__global__ __launch_bounds__(320) void gnn_final_k(const uint16_t* __restrict__ sumh,
                                                   const float* __restrict__ wc,
                                                   const float* __restrict__ bc,
                                                   float* __restrict__ out, int n) {
    __shared__ float a[64 * HID];  // 32 KB, float4 block (r, c4) at r*32 + (c4 ^ (r&7))
    const int tx = threadIdx.x % 10;
    const int ty = threadIdx.x / 10;
    const int row0 = blockIdx.x * 64;

    {
        const uint4* S8 = (const uint4*)sumh;  // 8 bf16 per uint4; 16 per row
        float4* s4 = (float4*)a;
        for (int idx = threadIdx.x; idx < 64 * 16; idx += 320) {
            int r = idx >> 4, c8 = idx & 15;
            uint4 v = make_uint4(0u, 0u, 0u, 0u);
            if (row0 + r < n) v = S8[(size_t)(row0 + r) * 16 + c8];
            float4 f0 = make_float4(bf_lo(v.x), bf_hi(v.x), bf_lo(v.y), bf_hi(v.y));
            float4 f1 = make_float4(bf_lo(v.z), bf_hi(v.z), bf_lo(v.w), bf_hi(v.w));
            s4[r * 32 + ((2 * c8) ^ (r & 7))] = f0;
            s4[r * 32 + ((2 * c8 + 1) ^ (r & 7))] = f1;
        }
    }
    __syncthreads();

    float acc[2][4];
    {
        float b0 = bc[tx * 4], b1 = bc[tx * 4 + 1], b2 = bc[tx * 4 + 2], b3 = bc[tx * 4 + 3];
        acc[0][0] = b0; acc[0][1] = b1; acc[0][2] = b2; acc[0][3] = b3;
        acc[1][0] = b0; acc[1][1] = b1; acc[1][2] = b2; acc[1][3] = b3;
    }
    const float* wp = wc + tx * 4;
    const float4* s4 = (const float4*)a;

#pragma unroll 2
    for (int k = 0; k < HID; k += 4) {
        int c4 = k >> 2;
        float ar[2][4];
#pragma unroll
        for (int r = 0; r < 2; ++r) {
            int row = ty * 2 + r;
            *(float4*)&ar[r][0] = s4[row * 32 + (c4 ^ (row & 7))];
        }
#pragma unroll
        for (int kk = 0; kk < 4; ++kk) {
            float4 w = *(const float4*)(wp + (size_t)(k + kk) * OUTD);
#pragma unroll
            for (int r = 0; r < 2; ++r) {
                acc[r][0] += ar[r][kk] * w.x;
                acc[r][1] += ar[r][kk] * w.y;
                acc[r][2] += ar[r][kk] * w.z;
                acc[r][3] += ar[r][kk] * w.w;
            }
        }
    }

#pragma unroll
    for (int r = 0; r < 2; ++r) {
        int row = row0 + ty * 2 + r;
        if (row < n) {
            float4 v = make_float4(acc[r][0], acc[r][1], acc[r][2], acc[r][3]);
            *(float4*)(out + (size_t)row * OUTD + tx * 4) = v;
        }
    }
}

// ---------------- launch ----------------

extern "C" void kernel_launch(void* const* d_in, const int* in_sizes, int n_in,
                              void* d_out, int out_size, void* d_ws, size_t ws_size,
                              hipStream_t stream) {
    const int N = in_sizes[0] / HID;   // 100000
    const int E = in_sizes[7] / 2;     // 1600000

    const float* x  = (const float*)d_in[0];
    const float* W1 = (const float*)d_in[1];
    const float* b1 = (const float*)d_in[2];
    const float* W2 = (const float*)d_in[3];
    const float* b2 = (const float*)d_in[4];
    const float* Wc = (const float*)d_in[5];
    const float* bc = (const float*)d_in[6];
    const int* edges = (const int*)d_in[7];
    float* out = (float*)d_out;

    // workspace carve-up (256B aligned)
    char* w = (char*)d_ws;
    auto alloc = [&](size_t bytes) -> char* {
        char* p = w;
        w += (bytes + 255) & ~(size_t)255;
        return p;
    };
    uint16_t* hbuf  = (uint16_t*)alloc((size_t)N * HID * 2);  // h' bf16 (both layers)
    uint16_t* bufBh = (uint16_t*)alloc((size_t)N * HID * 2);  // bf16 out1, then bf16 sum
    int*   rowptr  = (int*)alloc((size_t)(N + 1) * 4);
    int*   colidx  = (int*)alloc((size_t)(E + N) * 4);
    float* dinv    = (float*)alloc((size_t)N * 4);
    uint32_t* pairbuf = (uint32_t*)alloc((size_t)E * 4);
    int*   bcnt      = (int*)alloc(512 * 4);
    int*   bucketoff = (int*)alloc(513 * 4);
    int*   pcur      = (int*)alloc(512 * 4);
    uint16_t* w1s  = (uint16_t*)alloc(HID * HID * 2);
    uint16_t* w2s  = (uint16_t*)alloc(HID * HID * 2);

    const int NB = (N + 255) >> BSH;   // buckets (391)
    const int nEB = (E + EPB - 1) / EPB;

    hipMemsetAsync(bcnt, 0, 512 * 4, stream);

    gnn_hist_k<<<nEB, 256, 0, stream>>>(edges, bcnt, E, NB);
    gnn_bucketscan_k<<<17, 512, 0, stream>>>(bcnt, bucketoff, pcur, W1, W2, w1s, w2s, N, NB);
    gnn_bucket_scatter_k<<<nEB, 256, 0, stream>>>(edges, pcur, pairbuf, E, NB);
    gnn_build_csr_k<<<NB, 256, 0, stream>>>(pairbuf, bucketoff, rowptr, dinv, colidx, N);

    // layer 1: h1' = bf16(dinv * (x @ W1)) ; bufBh = bf16(relu(dinv*agg(h1') + b1))
    gnn_gemm_mfma_k<false><<<(N + 63) / 64, 256, 0, stream>>>(x, (const uint32_t*)w1s, dinv, hbuf, N);
    gnn_aggregate_k<<<(N + 3) / 4, 256, 0, stream>>>((const uint4*)hbuf, rowptr, colidx,
                                                     dinv, b1, nullptr, bufBh, N);
    // layer 2: h2' = bf16(dinv * (out1 @ W2)) ; bufBh = bf16(relu(...) + out1) in place
    gnn_gemm_mfma_k<true><<<(N + 63) / 64, 256, 0, stream>>>(bufBh, (const uint32_t*)w2s, dinv, hbuf, N);
    gnn_aggregate_k<<<(N + 3) / 4, 256, 0, stream>>>((const uint4*)hbuf, rowptr, colidx,
                                                     dinv, b2, bufBh, bufBh, N);
    // head
    gnn_final_k<<<(N + 63) / 64, 320, 0, stream>>>(bufBh, Wc, bc, out, N);
}